// Round 2
// baseline (19.832 us; speedup 1.0000x reference)
//
#include <hip/hip_runtime.h>

#define NATOMS 25000
#define NSP 64
#define NRANGE 16
#define RSIZE ((NATOMS + NRANGE - 1) / NRANGE)   // 1563 atoms per range
#define SCAN_IT ((RSIZE + 255) / 256)            // 7

typedef short bf16x8 __attribute__((ext_vector_type(8)));   // 8 bf16 = 4 VGPRs
typedef float f32x4  __attribute__((ext_vector_type(4)));
typedef unsigned short u16;
typedef __attribute__((address_space(3))) unsigned int  lds_u32;
typedef __attribute__((address_space(1))) unsigned int  gbl_u32;

// f32 -> bf16 round-to-nearest-even
__device__ __forceinline__ u16 f2bf(float f) {
  unsigned u = __float_as_uint(f);
  u += 0x7fffu + ((u >> 16) & 1u);
  return (u16)(u >> 16);
}

// ---- prep: W f32 -> bf16, plain row-major [s][o][i]. 512 blocks x 256 thr x 8 elems.
__global__ __launch_bounds__(256)
void conv_w_kernel(const float* __restrict__ w, u16* __restrict__ wbf) {
  int i = (blockIdx.x * 256 + threadIdx.x) * 8;
  const float4* p = (const float4*)(w + i);
  float4 v0 = p[0], v1 = p[1];
  union { u16 h[8]; bf16x8 v; } uu;
  uu.h[0] = f2bf(v0.x); uu.h[1] = f2bf(v0.y);
  uu.h[2] = f2bf(v0.z); uu.h[3] = f2bf(v0.w);
  uu.h[4] = f2bf(v1.x); uu.h[5] = f2bf(v1.y);
  uu.h[6] = f2bf(v1.z); uu.h[7] = f2bf(v1.w);
  *(bf16x8*)(wbf + i) = uu.v;
}

__global__ __launch_bounds__(256)
void zcl_kernel(const float* __restrict__ feat,
                const int*   __restrict__ sp,
                const u16*   __restrict__ wbf,
                const float* __restrict__ bias,
                float*       __restrict__ out)
{
  // W[o][i] bf16 in LDS; 16B chunks XOR-swizzled by (row&7) so MFMA B-frag
  // ds_read_b128 spreads over all 32 banks. Staged via global_load_lds with
  // the swizzle applied on the per-lane GLOBAL source address (m173 pattern:
  // LDS dest must stay linear).
  __shared__ u16 Ws[128 * 128];              // 32 KiB
  __shared__ u16 As[16 * 128];               // 4 KiB, same swizzle
  __shared__ u16 list[((RSIZE + 15) & ~15) + 16];
  __shared__ int nM;

  const int tid = threadIdx.x;
  const int bid = blockIdx.x;
  const int s  = bid >> 4;
  const int r  = bid & (NRANGE - 1);
  const int lo = r * RSIZE;
  const int hi = (lo + RSIZE < NATOMS) ? (lo + RSIZE) : NATOMS;

  const int wv   = tid >> 6;
  const int lane = tid & 63;
  const int l16  = lane & 15;
  const int kq   = lane >> 4;
  const int o0   = wv * 32 + l16;

  // --- issue order matters for counted-vmcnt overlap: bias, sp, THEN staging,
  // so scan's use of sp waits only on the older bias+sp loads (vmcnt(8)),
  // leaving the 8 W-staging loads in flight across the scan compute.
  const float bv0 = bias[s * 128 + o0];
  const float bv1 = bias[s * 128 + o0 + 16];

  int spv[SCAN_IT];
  #pragma unroll
  for (int i = 0; i < SCAN_IT; ++i) {
    int a = lo + i * 256 + tid;
    spv[i] = (a < hi) ? sp[a] : -1;
  }

  // --- async W stage: 2048 16B chunks, 8 per thread. LDS dest linear
  // (wave-uniform base + lane*16); source pre-swizzled per-lane.
  const u16* wsrc = wbf + (size_t)s * (128 * 128);
  #pragma unroll
  for (int j = 0; j < 8; ++j) {
    int m   = j * 256 + tid;                 // LDS chunk index (linear)
    int row = m >> 4;
    int cs  = m & 15;                        // LDS slot -> source chunk cs^(row&7)
    const u16* src = wsrc + row * 128 + ((cs ^ (row & 7)) << 3);
    u16* dst = &Ws[(j * 256 + (tid & ~63)) * 8];   // wave-uniform
    __builtin_amdgcn_global_load_lds((gbl_u32*)src, (lds_u32*)dst, 16, 0, 0);
  }

  if (tid == 0) nM = 0;
  asm volatile("s_waitcnt lgkmcnt(0)" ::: "memory");  // nM=0 visible
  __builtin_amdgcn_s_barrier();                       // raw: does NOT drain vmcnt

  // --- scan compute (overlaps in-flight W staging) ---
  #pragma unroll
  for (int i = 0; i < SCAN_IT; ++i) {
    bool m = (spv[i] == s);
    unsigned long long mk = __ballot(m);
    int base = 0;
    if (lane == 0) base = atomicAdd(&nM, __popcll(mk));
    base = __shfl(base, 0);
    if (m) list[base + __popcll(mk & ((1ull << lane) - 1ull))] = (u16)(lo + i * 256 + tid);
  }
  __syncthreads();   // drains staging too; nM/list/Ws all ready

  const int nMatch = nM;
  const int ntile  = (nMatch + 15) >> 4;
  if (ntile == 0) return;

  // --- tile loop with register prefetch of the next A-tile (T14) ---
  const int grow = tid >> 4, gc = tid & 15;  // 16 thr/row gather
  float4 pv0, pv1;
  {
    int li = grow;
    int atom = list[li < nMatch ? li : 0];
    const float4* xg = (const float4*)(feat + (size_t)atom * 128);
    pv0 = xg[gc * 2]; pv1 = xg[gc * 2 + 1];
  }

  for (int t = 0; t < ntile; ++t) {
    // write prefetched rows -> As (convert f32->bf16, swizzled)
    union { u16 h[8]; bf16x8 v; } uu;
    uu.h[0] = f2bf(pv0.x); uu.h[1] = f2bf(pv0.y);
    uu.h[2] = f2bf(pv0.z); uu.h[3] = f2bf(pv0.w);
    uu.h[4] = f2bf(pv1.x); uu.h[5] = f2bf(pv1.y);
    uu.h[6] = f2bf(pv1.z); uu.h[7] = f2bf(pv1.w);
    *(bf16x8*)&As[grow * 128 + ((gc ^ (grow & 7)) << 3)] = uu.v;
    __syncthreads();                         // As ready

    // issue next tile's gather (overlaps MFMA + store)
    if (t + 1 < ntile) {
      int li = (t + 1) * 16 + grow;
      int atom = list[li < nMatch ? li : 0];
      const float4* xg = (const float4*)(feat + (size_t)atom * 128);
      pv0 = xg[gc * 2]; pv1 = xg[gc * 2 + 1];
    }

    // 16(M) x 32(N per wave) x 128(K): 8 MFMAs
    f32x4 acc0 = {0.f, 0.f, 0.f, 0.f};
    f32x4 acc1 = {0.f, 0.f, 0.f, 0.f};
    const int br0 = wv * 32 + l16;
    const int br1 = br0 + 16;
    #pragma unroll
    for (int ks = 0; ks < 4; ++ks) {
      int slot = ks * 4 + kq;
      bf16x8 av = *(const bf16x8*)&As[l16 * 128 + ((slot ^ (l16 & 7)) << 3)];
      bf16x8 b0 = *(const bf16x8*)&Ws[br0 * 128 + ((slot ^ (br0 & 7)) << 3)];
      bf16x8 b1 = *(const bf16x8*)&Ws[br1 * 128 + ((slot ^ (br1 & 7)) << 3)];
      acc0 = __builtin_amdgcn_mfma_f32_16x16x32_bf16(av, b0, acc0, 0, 0, 0);
      acc1 = __builtin_amdgcn_mfma_f32_16x16x32_bf16(av, b1, acc1, 0, 0, 0);
    }

    // store: D row=(lane>>4)*4+q (atom), col=lane&15 (output)
    #pragma unroll
    for (int q = 0; q < 4; ++q) {
      int li = t * 16 + kq * 4 + q;
      if (li < nMatch) {
        int atom = list[li];
        float* op = out + (size_t)atom * 128 + o0;
        op[0]  = acc0[q] + bv0;
        op[16] = acc1[q] + bv1;
      }
    }
    __syncthreads();                         // As readers done -> next write ok
  }
}

extern "C" void kernel_launch(void* const* d_in, const int* in_sizes, int n_in,
                              void* d_out, int out_size, void* d_ws, size_t ws_size,
                              hipStream_t stream) {
  const float* feat   = (const float*)d_in[0];
  const int*   sp     = (const int*)d_in[1];
  const float* weight = (const float*)d_in[2];
  const float* bias   = (const float*)d_in[3];
  float*       out    = (float*)d_out;
  u16*         wbf    = (u16*)d_ws;          // 64*128*128*2 B = 2 MiB scratch

  conv_w_kernel<<<512, 256, 0, stream>>>(weight, wbf);
  zcl_kernel<<<NSP * NRANGE, 256, 0, stream>>>(feat, sp, wbf, bias, out);
}

// Round 3
// 17.164 us; speedup vs baseline: 1.1554x; 1.1554x over previous
//
#include <hip/hip_runtime.h>

#define NATOMS 25000
#define NSP 64
#define NRANGE 4
#define RSIZE ((NATOMS + NRANGE - 1) / NRANGE)   // 6250 atoms per range
#define SCAN_IT ((RSIZE + 255) / 256)            // 25

typedef short bf16x8 __attribute__((ext_vector_type(8)));   // 8 bf16 = 4 VGPRs
typedef float f32x4  __attribute__((ext_vector_type(4)));
typedef unsigned short u16;

// f32 -> bf16 round-to-nearest-even
__device__ __forceinline__ u16 f2bf(float f) {
  unsigned u = __float_as_uint(f);
  u += 0x7fffu + ((u >> 16) & 1u);
  return (u16)(u >> 16);
}

__global__ __launch_bounds__(256)
void zcl_kernel(const float* __restrict__ feat,
                const int*   __restrict__ sp,
                const float* __restrict__ weight,
                const float* __restrict__ bias,
                float*       __restrict__ out)
{
  // W[o][i] bf16, rows of 128 elems; 16B chunks XOR-swizzled by (row&7) so
  // B-frag ds_read_b128 (lanes differ in row, fixed k-chunk) spreads banks.
  __shared__ u16 Ws[128 * 128];     // 32 KiB
  __shared__ u16 list[RSIZE];       // 12.5 KiB
  __shared__ int nM;

  const int tid = threadIdx.x;
  const int bid = blockIdx.x;
  const int s  = bid >> 2;          // species
  const int r  = bid & 3;           // atom range
  const int lo = r * RSIZE;
  const int hi = (lo + RSIZE < NATOMS) ? (lo + RSIZE) : NATOMS;

  const int wv   = tid >> 6;        // wave 0..3: owns tiles t = wv, wv+4, ...
  const int lane = tid & 63;
  const int l16  = lane & 15;
  const int kq   = lane >> 4;

  // ---- 1) issue sp-range preload (25 coalesced dwords/thread) ----
  int spv[SCAN_IT];
  #pragma unroll
  for (int i = 0; i < SCAN_IT; ++i) {
    int a = lo + i * 256 + tid;
    spv[i] = (a < hi) ? sp[a] : -1;
  }

  // bias hoist (L2-hot), 8 dwords/thread
  float bv[8];
  #pragma unroll
  for (int nf = 0; nf < 8; ++nf) bv[nf] = bias[s * 128 + l16 + 16 * nf];

  // ---- 2) issue W[s] f32 loads into regs (16 float4/thread, stay in flight) ----
  const float4* wg = (const float4*)(weight + (size_t)s * (128 * 128));
  float4 wv0[8], wv1[8];
  #pragma unroll
  for (int j = 0; j < 8; ++j) {
    int m = j * 256 + tid;          // chunk 0..2047: row = m>>4, 8-elem group c = m&15
    int row = m >> 4, c = m & 15;
    wv0[j] = wg[row * 32 + c * 2];
    wv1[j] = wg[row * 32 + c * 2 + 1];
  }

  // ---- 3) nM init; raw barrier (lgkm-only drain, VMEM stays in flight) ----
  if (tid == 0) nM = 0;
  asm volatile("s_waitcnt lgkmcnt(0)" ::: "memory");
  __builtin_amdgcn_s_barrier();
  __builtin_amdgcn_sched_barrier(0);

  // ---- 4) compact scan (sp arrives first in VMEM FIFO; W still loading) ----
  #pragma unroll
  for (int i = 0; i < SCAN_IT; ++i) {
    bool m = (spv[i] == s);
    unsigned long long mk = __ballot(m);
    int base = 0;
    if (lane == 0) base = atomicAdd(&nM, __popcll(mk));
    base = __shfl(base, 0);
    if (m) list[base + __popcll(mk & ((1ull << lane) - 1ull))] = (u16)(lo + i * 256 + tid);
  }

  // ---- 5) convert W -> bf16, swizzled ds_write ----
  #pragma unroll
  for (int j = 0; j < 8; ++j) {
    int m = j * 256 + tid;
    int row = m >> 4, c = m & 15;
    union { u16 h[8]; bf16x8 v; } uu;
    uu.h[0] = f2bf(wv0[j].x); uu.h[1] = f2bf(wv0[j].y);
    uu.h[2] = f2bf(wv0[j].z); uu.h[3] = f2bf(wv0[j].w);
    uu.h[4] = f2bf(wv1[j].x); uu.h[5] = f2bf(wv1[j].y);
    uu.h[6] = f2bf(wv1[j].z); uu.h[7] = f2bf(wv1[j].w);
    *(bf16x8*)&Ws[row * 128 + ((c ^ (row & 7)) << 3)] = uu.v;
  }

  __syncthreads();   // Ws + list + nM all visible

  const int nMatch = nM;
  const int ntile  = (nMatch + 15) >> 4;
  if (ntile == 0) return;

  // ---- 6) wave-independent tile loop, no barriers ----
  // A-frag: lane (l16,kq) holds feat[atom(l16)][k=ks*32+kq*8 .. +8] per ks.
  int t = wv;
  float4 pf[8];
  {
    int li = t * 16 + l16;
    int atomA = list[li < nMatch ? li : 0];
    const float4* xg = (const float4*)(feat + (size_t)atomA * 128);
    #pragma unroll
    for (int ks = 0; ks < 4; ++ks) {
      pf[2 * ks]     = xg[ks * 8 + kq * 2];
      pf[2 * ks + 1] = xg[ks * 8 + kq * 2 + 1];
    }
  }

  for (; t < ntile; t += 4) {
    float4 fv[8];
    #pragma unroll
    for (int u = 0; u < 8; ++u) fv[u] = pf[u];

    // prefetch next tile of this wave (overlaps convert+MFMA+stores)
    if (t + 4 < ntile) {
      int li = (t + 4) * 16 + l16;
      int atomA = list[li < nMatch ? li : 0];
      const float4* xg = (const float4*)(feat + (size_t)atomA * 128);
      #pragma unroll
      for (int ks = 0; ks < 4; ++ks) {
        pf[2 * ks]     = xg[ks * 8 + kq * 2];
        pf[2 * ks + 1] = xg[ks * 8 + kq * 2 + 1];
      }
    }

    // convert A to bf16 frags
    bf16x8 av[4];
    #pragma unroll
    for (int ks = 0; ks < 4; ++ks) {
      union { u16 h[8]; bf16x8 v; } uu;
      uu.h[0] = f2bf(fv[2 * ks].x);     uu.h[1] = f2bf(fv[2 * ks].y);
      uu.h[2] = f2bf(fv[2 * ks].z);     uu.h[3] = f2bf(fv[2 * ks].w);
      uu.h[4] = f2bf(fv[2 * ks + 1].x); uu.h[5] = f2bf(fv[2 * ks + 1].y);
      uu.h[6] = f2bf(fv[2 * ks + 1].z); uu.h[7] = f2bf(fv[2 * ks + 1].w);
      av[ks] = uu.v;
    }

    // 16(M) x 128(N) x 128(K) per wave: 32 MFMAs, B from LDS (imm offsets)
    f32x4 acc[8];
    #pragma unroll
    for (int nf = 0; nf < 8; ++nf) acc[nf] = (f32x4){0.f, 0.f, 0.f, 0.f};
    #pragma unroll
    for (int ks = 0; ks < 4; ++ks) {
      int chunk = ((ks * 4 + kq) ^ (l16 & 7)) << 3;   // same for all nf (16nf keeps &7)
      #pragma unroll
      for (int nf = 0; nf < 8; ++nf) {
        bf16x8 b = *(const bf16x8*)&Ws[(l16 + 16 * nf) * 128 + chunk];
        acc[nf] = __builtin_amdgcn_mfma_f32_16x16x32_bf16(av[ks], b, acc[nf], 0, 0, 0);
      }
    }

    // store: D row(m) = kq*4+q -> atom; col = l16 -> out l16+16*nf
    #pragma unroll
    for (int q = 0; q < 4; ++q) {
      int li2 = t * 16 + kq * 4 + q;
      if (li2 < nMatch) {
        int atom = list[li2];
        float* op = out + (size_t)atom * 128 + l16;
        #pragma unroll
        for (int nf = 0; nf < 8; ++nf) op[16 * nf] = acc[nf][q] + bv[nf];
      }
    }
  }
}

extern "C" void kernel_launch(void* const* d_in, const int* in_sizes, int n_in,
                              void* d_out, int out_size, void* d_ws, size_t ws_size,
                              hipStream_t stream) {
  const float* feat   = (const float*)d_in[0];
  const int*   sp     = (const int*)d_in[1];
  const float* weight = (const float*)d_in[2];
  const float* bias   = (const float*)d_in[3];
  float*       out    = (float*)d_out;
  zcl_kernel<<<NSP * NRANGE, 256, 0, stream>>>(feat, sp, weight, bias, out);
}